// Round 17
// baseline (508.553 us; speedup 1.0000x reference)
//
#include <hip/hip_runtime.h>

typedef __attribute__((ext_vector_type(8))) short short8;
typedef __attribute__((ext_vector_type(4))) float f32x4;

#define T_TOK  131072
#define DMODEL 256
#define DHID   512
#define NEXP   8

// ---------------- ws layout (bytes) ----------------
// xb        : 0          size 67108864   (T*256 bf16)
// P1        : 67108864   size 2097152    W1 panels [e][kc4][512][64] pre-swizzled
// P2        : 69206016   size 2097152    W2 panels [e][kc8][256][64] pre-swizzled
// tok_list  : 71303168   size 1064960    (padded-base layout)
// wt_list   : 72368128   size 1064960
// pack      : 73433088   size 524288
// tkw/inv   : 73957376   size 1048576
// part_cnt  : 75005952   size 65536
// part_psum : 75071488   size 65536
// block_off : 75137024   size 65536
// cnt_total : 75202560   size 64         int[16]: counts + 256-PADDED bases
// gate_d    : 75235328   size 16384      gate as fp64 [8][256]
// Hp        : 75497472   size 270532608  H panels; gemm2c reuses first half for Y

__device__ __forceinline__ unsigned short f2bf(float f) {
  unsigned int u = __float_as_uint(f);
  u = (u + 0x7FFFu + ((u >> 16) & 1u)) >> 16;
  return (unsigned short)u;
}
__device__ __forceinline__ float bf2f(unsigned short u) {
  return __uint_as_float(((unsigned)u) << 16);
}

__device__ __forceinline__ void gload16(const void* g, void* l) {
  __builtin_amdgcn_global_load_lds(
      (const __attribute__((address_space(1))) void*)g,
      (__attribute__((address_space(3))) void*)l, 16, 0, 0);
}

// ---------------- weight fp32 -> bf16 K-panels (pre-swizzled) + gate fp64 ----------------
__global__ void k_wconv(const float* __restrict__ w1, const float* __restrict__ w2,
                        const float* __restrict__ gate,
                        unsigned short* __restrict__ P1, unsigned short* __restrict__ P2,
                        double* __restrict__ gate_d) {
  int g = blockIdx.x * 256 + threadIdx.x;  // 131072 threads
  if (g < 2048) gate_d[g] = (double)gate[g];
  int e = g >> 14, rem = g & 16383;
  {
    int row = rem >> 5, c = rem & 31;      // 512 rows x 32 chunks (K=256)
    int kc = c >> 3, cs = c & 7;
    const float* s = w1 + ((size_t)e * DHID + row) * DMODEL + c * 8;
    short8 v;
#pragma unroll
    for (int j = 0; j < 8; ++j) v[j] = (short)f2bf(s[j]);
    size_t dc = ((size_t)(e * 4 + kc) * 512 + row) * 8 + (cs ^ (row & 7));
    *(short8*)(P1 + dc * 8) = v;
  }
  {
    int row = rem >> 6, c = rem & 63;      // 256 rows x 64 chunks (K=512)
    int kc = c >> 3, cs = c & 7;
    const float* s = w2 + ((size_t)e * DMODEL + row) * DHID + c * 8;
    short8 v;
#pragma unroll
    for (int j = 0; j < 8; ++j) v[j] = (short)f2bf(s[j]);
    size_t dc = ((size_t)(e * 8 + kc) * 256 + row) * 8 + (cs ^ (row & 7));
    *(short8*)(P2 + dc * 8) = v;
  }
}

// ---------------- router: token-per-lane, fp64 logits via s_load'd gate_d ----------------
__global__ __launch_bounds__(256, 2) void k_router(
    const float* __restrict__ x, const double* __restrict__ gd,
    unsigned short* __restrict__ xb, int* __restrict__ pack, float2* __restrict__ tkw,
    int* __restrict__ part_cnt, float* __restrict__ part_psum) {
  __shared__ float xs[16384];       // 64 rows x 256 (swizzled slots), 64KB
  __shared__ double red[1024];      // 256 thr x 4 experts, 8KB
  __shared__ int s_cnt[NEXP];
  __shared__ float s_ps[NEXP];
  int tid = threadIdx.x;
  int tok = tid & 63, q = tid >> 6;
  int qu = __builtin_amdgcn_readfirstlane(q);   // wave-uniform quarter -> s_loads

  for (int c = 0; c < 4; ++c) {
    if (tid < NEXP) { s_cnt[tid] = 0; s_ps[tid] = 0.f; }
    int tb = (blockIdx.x << 8) + (c << 6);
    __syncthreads();  // xs free (prev chunk done) + hist reset visible

#pragma unroll
    for (int i = 0; i < 16; ++i) {
      int idx = i * 256 + tid;
      int row = idx >> 6, c4 = (idx & 63) << 2;
      float4 v = *(const float4*)(x + (size_t)(tb + row) * 256 + c4);
      int sw = row & 31;
      float* xr = xs + row * 256;
      xr[(c4 + 0) ^ sw] = v.x;
      xr[(c4 + 1) ^ sw] = v.y;
      xr[(c4 + 2) ^ sw] = v.z;
      xr[(c4 + 3) ^ sw] = v.w;
      ushort4 u4;
      u4.x = f2bf(v.x); u4.y = f2bf(v.y); u4.z = f2bf(v.z); u4.w = f2bf(v.w);
      *(ushort4*)(xb + (size_t)(tb + row) * 256 + c4) = u4;
    }
    __syncthreads();

    double acc[8] = {0, 0, 0, 0, 0, 0, 0, 0};
    {
      int sw = tok & 31;
      const float* xr = xs + tok * 256;
#pragma unroll 4
      for (int d0 = 0; d0 < 64; ++d0) {
        int d = (qu << 6) + d0;
        double xv = (double)xr[d ^ sw];
#pragma unroll
        for (int e = 0; e < 8; ++e) acc[e] += xv * gd[e * 256 + d];
      }
    }

    double l[8];
#pragma unroll
    for (int j = 0; j < 4; ++j) red[tid * 4 + j] = acc[j];
    __syncthreads();
    if (tid < 64) {
#pragma unroll
      for (int j = 0; j < 4; ++j)
        l[j] = red[tid * 4 + j] + red[(64 + tid) * 4 + j] +
               red[(128 + tid) * 4 + j] + red[(192 + tid) * 4 + j];
    }
    __syncthreads();
#pragma unroll
    for (int j = 0; j < 4; ++j) red[tid * 4 + j] = acc[4 + j];
    __syncthreads();
    if (tid < 64) {
#pragma unroll
      for (int j = 0; j < 4; ++j)
        l[4 + j] = red[tid * 4 + j] + red[(64 + tid) * 4 + j] +
                   red[(128 + tid) * 4 + j] + red[(192 + tid) * 4 + j];
      int t = tb + tid;
      int i1 = 0;
#pragma unroll
      for (int e = 1; e < NEXP; ++e) if (l[e] > l[i1]) i1 = e;
      int i2 = (i1 == 0) ? 1 : 0;
#pragma unroll
      for (int e = 0; e < NEXP; ++e) if (e != i1 && l[e] > l[i2]) i2 = e;
      double m = l[0];
#pragma unroll
      for (int e = 1; e < NEXP; ++e) m = (l[e] > m) ? l[e] : m;
      float pe[NEXP]; float s = 0.f;
#pragma unroll
      for (int e = 0; e < NEXP; ++e) { pe[e] = __expf((float)(l[e] - m)); s += pe[e]; }
      float inv = 1.f / s;
      float p1 = pe[i1] * inv, p2 = pe[i2] * inv;
      float wn = 1.f / (p1 + p2);
      pack[t] = i1 | (i2 << 8);
      tkw[t] = make_float2(p1 * wn, p2 * wn);
      atomicAdd(&s_cnt[i1], 1); atomicAdd(&s_cnt[i2], 1);
#pragma unroll
      for (int e = 0; e < NEXP; ++e) atomicAdd(&s_ps[e], pe[e] * inv);
    }
    __syncthreads();
    if (tid < NEXP) {
      part_cnt[(blockIdx.x * 4 + c) * NEXP + tid] = s_cnt[tid];
      part_psum[(blockIdx.x * 4 + c) * NEXP + tid] = s_ps[tid];
    }
  }
}

// ---------------- scan: offsets, totals, 256-PADDED expert bases, aux loss ----------------
__global__ __launch_bounds__(512) void k_scan(
    const int* __restrict__ part_cnt, const float* __restrict__ part_psum,
    int* __restrict__ block_off, int* __restrict__ cnt_total, float* __restrict__ out) {
  __shared__ float s_ps[NEXP];
  __shared__ int s_ct[NEXP];
  int lane = threadIdx.x & 63, wv = threadIdx.x >> 6;
  int base = lane * 32;
  int lsum = 0; float ps = 0.f;
#pragma unroll 8
  for (int j = 0; j < 32; ++j) {
    lsum += part_cnt[(base + j) * NEXP + wv];
    ps += part_psum[(base + j) * NEXP + wv];
  }
  int incl = lsum;
#pragma unroll
  for (int d = 1; d < 64; d <<= 1) { int t = __shfl_up(incl, d); if (lane >= d) incl += t; }
  int run = incl - lsum;
#pragma unroll 8
  for (int j = 0; j < 32; ++j) {
    int v = part_cnt[(base + j) * NEXP + wv];
    block_off[(base + j) * NEXP + wv] = run;
    run += v;
  }
#pragma unroll
  for (int d = 32; d; d >>= 1) ps += __shfl_xor(ps, d);
  int total = __shfl(incl, 63);
  if (lane == 0) { cnt_total[wv] = total; s_ct[wv] = total; s_ps[wv] = ps; }
  __syncthreads();
  if (threadIdx.x == 0) {
    double aux = 0.0; int rb = 0;
    for (int e = 0; e < NEXP; ++e) {
      aux += ((double)s_ct[e] / 131072.0) * ((double)s_ps[e] / 131072.0);
      cnt_total[8 + e] = rb;
      rb += (s_ct[e] + 255) & ~255;   // 256-aligned padded base
    }
    out[33554432] = (float)(8.0 * aux);
  }
}

// ---------------- scatter: per-expert lists + inverse map (over tkw) ----------------
__global__ void k_scatter(const int* __restrict__ pack, float2* tkw,
                          const int* __restrict__ block_off, const int* __restrict__ cnt_total,
                          int* __restrict__ tok_list, float* __restrict__ wt_list) {
  __shared__ int s_loc[NEXP];
  int tid = threadIdx.x;
  if (tid < NEXP) s_loc[tid] = 0;
  __syncthreads();
  int t = (blockIdx.x << 6) + tid;
  int p = pack[t];
  float2 wv = tkw[t];
  int e1 = p & 255, e2 = (p >> 8) & 255;
  int o1 = block_off[blockIdx.x * NEXP + e1];
  int p1 = atomicAdd(&s_loc[e1], 1);
  int i1 = cnt_total[8 + e1] + o1 + p1;
  tok_list[i1] = t; wt_list[i1] = wv.x;
  int o2 = block_off[blockIdx.x * NEXP + e2];
  int p2 = atomicAdd(&s_loc[e2], 1);
  int i2 = cnt_total[8 + e2] + o2 + p2;
  tok_list[i2] = t; wt_list[i2] = wv.y;
  tkw[t] = make_float2(__int_as_float(i1), __int_as_float(i2));
}

// ---------------- grouped GEMM1 + silu -> Hp panels ----------------
// R17: epilogue rebuilt for WRITE COALESCING. Bounce stride 264 (bank-spread);
// wave w owns panel kc_l=w>>1, half w&1; each store inst = 64x16B fully linear
// (1KB contiguous). Content mapping (slot s @ row r holds chunk s^(r&7)) is
// IDENTICAL to before -> gemm2c reader unchanged. Padded rows store zeros.
__global__ __launch_bounds__(512, 2) void k_gemm1(
    const unsigned short* __restrict__ xb, const unsigned short* __restrict__ P1,
    const float* __restrict__ b1, const int* __restrict__ tok_list,
    const int* __restrict__ cnt_total, unsigned short* __restrict__ Hp) {
  __shared__ __align__(16) unsigned short buf[65536];
  __shared__ int s_tok[128];

  int bid = (blockIdx.x & 7) * 514 + (blockIdx.x >> 3);  // grid 4112 = 8*514
  int e = -1, loc = 0, cum = 0, cnte = 0;
#pragma unroll
  for (int ee = 0; ee < NEXP; ++ee) {
    int ct = cnt_total[ee];
    int nb = ((ct + 127) >> 7) * 2;
    if (e < 0 && bid < cum + nb) { e = ee; loc = bid - cum; cnte = ct; }
    cum += nb;
  }
  if (e < 0) return;
  int mi = loc >> 1, ni = loc & 1;
  int nv = cnte - (mi << 7); if (nv > 128) nv = 128;
  int hbp = cnt_total[8 + e];

  int tid = threadIdx.x;
  int lane = tid & 63, w = tid >> 6, l15 = lane & 15, lg = lane >> 4;
  int wr = w >> 2, wc = w & 3;

  float b1v[4];
#pragma unroll
  for (int nt = 0; nt < 4; ++nt)
    b1v[nt] = b1[e * DHID + ni * 256 + wc * 64 + nt * 16 + l15];

  if (tid < 128) s_tok[tid] = tok_list[hbp + (mi << 7) + (tid < nv ? tid : nv - 1)];
  __syncthreads();

  int ar0 = tid >> 5;
  int ac = tid & 31;
#pragma unroll
  for (int i = 0; i < 8; ++i) {
    int row = i * 16 + ar0;
    gload16(xb + (size_t)s_tok[row] * DMODEL + (size_t)((ac ^ (row & 7)) << 3),
            &buf[(size_t)(i * 512 + w * 64) * 8]);
  }
  auto stage_b = [&](int kc) {
    const unsigned short* src = P1 + ((size_t)(e * 4 + kc) * 512 + ni * 256) * 64;
    int d = 32768 + (kc & 1) * 16384;
#pragma unroll
    for (int i = 0; i < 4; ++i) {
      int cidx = i * 512 + tid;
      gload16(src + (size_t)cidx * 8, &buf[d + (i * 512 + w * 64) * 8]);
    }
  };
  stage_b(0);
  asm volatile("s_waitcnt vmcnt(0)" ::: "memory");
  __builtin_amdgcn_s_barrier();
  __builtin_amdgcn_sched_barrier(0);

  int aidx[4][2], bidx[4][2];
#pragma unroll
  for (int mt = 0; mt < 4; ++mt) {
    int r = wr * 64 + mt * 16 + l15, r7 = r & 7;
#pragma unroll
    for (int ks = 0; ks < 2; ++ks) aidx[mt][ks] = r * 256 + (((ks * 4 + lg) ^ r7) << 3);
  }
#pragma unroll
  for (int nt = 0; nt < 4; ++nt) {
    int r = wc * 64 + nt * 16 + l15, r7 = r & 7;
#pragma unroll
    for (int ks = 0; ks < 2; ++ks) bidx[nt][ks] = r * 64 + (((ks * 4 + lg) ^ r7) << 3);
  }

  f32x4 acc[4][4];
#pragma unroll
  for (int mt = 0; mt < 4; ++mt)
#pragma unroll
    for (int nt = 0; nt < 4; ++nt) acc[mt][nt] = (f32x4){0.f, 0.f, 0.f, 0.f};

  for (int s = 0; s < 4; ++s) {
    if (s < 3) stage_b(s + 1);
    int abase = s * 64;
    int bbase = 32768 + (s & 1) * 16384;
#pragma unroll
    for (int ks = 0; ks < 2; ++ks) {
      short8 a[4], b[4];
#pragma unroll
      for (int mt = 0; mt < 4; ++mt) a[mt] = *(const short8*)&buf[abase + aidx[mt][ks]];
#pragma unroll
      for (int nt = 0; nt < 4; ++nt) b[nt] = *(const short8*)&buf[bbase + bidx[nt][ks]];
#pragma unroll
      for (int mt = 0; mt < 4; ++mt)
#pragma unroll
        for (int nt = 0; nt < 4; ++nt)
          acc[mt][nt] = __builtin_amdgcn_mfma_f32_16x16x32_bf16(a[mt], b[nt], acc[mt][nt], 0, 0, 0);
    }
    asm volatile("s_waitcnt vmcnt(0)" ::: "memory");
    __builtin_amdgcn_s_barrier();
    __builtin_amdgcn_sched_barrier(0);
  }

  // epilogue pass 1: silu -> bounce buffer, row stride 264 (bank-spread),
  // chunk position p = (c3&24) | ((c3&7) ^ (row&7))   [same content involution]
#pragma unroll
  for (int mt = 0; mt < 4; ++mt) {
    int rbase0 = (wr * 64 + mt * 16) * 264;
#pragma unroll
    for (int nt = 0; nt < 4; ++nt) {
      int col = wc * 64 + nt * 16 + l15;
      int c3 = col >> 3, c7 = col & 7;
#pragma unroll
      for (int rr = 0; rr < 4; ++rr) {
        int lr = lg * 4 + rr;                // local row-in-16 (0..15)
        int r7 = lr & 7;                     // row&7 (rows are 0 mod 16 per mt)
        int p = (c3 & 24) | ((c3 & 7) ^ r7);
        float z = acc[mt][nt][rr] + b1v[nt];
        float sv = z * __builtin_amdgcn_rcpf(1.f + __expf(-z));
        buf[rbase0 + lr * 264 + (p << 3) + c7] =
            (unsigned short)(__float_as_uint(sv) >> 16);
      }
    }
  }
  __syncthreads();
  // epilogue pass 2: wave w -> panel kc_l=w>>1, rows half*64..+64; each inst
  // writes 1KB contiguous (lane -> row lane>>3, slot lane&7).
  {
    int blk = (hbp >> 8) + (mi >> 1);
    int rbase = (mi & 1) * 128;
    int kc_l = w >> 1, half = w & 1;
    int rl = lane >> 3, sl = lane & 7;
    unsigned short* pdst =
        Hp + ((size_t)(blk * 8 + ni * 4 + kc_l) * 256 + rbase + half * 64) * 64;
    short8 z8 = {0, 0, 0, 0, 0, 0, 0, 0};
#pragma unroll
    for (int j = 0; j < 8; ++j) {
      int r = half * 64 + j * 8 + rl;        // local row 0..127
      short8 v = (r < nv) ? *(const short8*)&buf[r * 264 + ((kc_l * 8 + sl) << 3)] : z8;
      *(short8*)&pdst[(size_t)(j * 8 + rl) * 64 + sl * 8] = v;
    }
  }
}

// ---------------- GEMM2 compute: K-loop w/ precomputed indices, trunc epilogue ----------
__global__ __launch_bounds__(512, 2) void k_gemm2c(
    unsigned short* Hp, const unsigned short* __restrict__ P2,
    const float* __restrict__ b2, const float* __restrict__ wt_list,
    const int* __restrict__ cnt_total) {
  __shared__ __align__(16) unsigned short buf[65536];
  __shared__ float s_wt[256];

  int bid = (blockIdx.x & 7) * 129 + (blockIdx.x >> 3);  // grid 1032 = 8*129
  int e = -1, mi = 0, cum = 0, cnte = 0;
#pragma unroll
  for (int ee = 0; ee < NEXP; ++ee) {
    int ct = cnt_total[ee];
    int nb = (ct + 255) >> 8;
    if (e < 0 && bid < cum + nb) { e = ee; mi = bid - cum; cnte = ct; }
    cum += nb;
  }
  if (e < 0) return;
  int nv = cnte - (mi << 8); if (nv > 256) nv = 256;
  int hbp = cnt_total[8 + e];
  int blk = (hbp >> 8) + mi;

  int tid = threadIdx.x;
  int lane = tid & 63, w = tid >> 6, l15 = lane & 15, lg = lane >> 4;
  int wr = w >> 2, wc = w & 3;

  float b2v[4];
#pragma unroll
  for (int nt = 0; nt < 4; ++nt)
    b2v[nt] = b2[e * DMODEL + wc * 64 + nt * 16 + l15];

  if (tid < 256) s_wt[tid] = (tid < nv) ? wt_list[hbp + (mi << 8) + tid] : 0.f;
  __syncthreads();

  auto stage = [&](int s) {
    int d = (s & 1) * 32768;
    const unsigned short* sa = Hp + (size_t)(blk * 8 + s) * 16384;
    const unsigned short* sb = P2 + (size_t)(e * 8 + s) * 16384;
#pragma unroll
    for (int i = 0; i < 4; ++i) {
      int c = i * 512 + tid;
      gload16(sa + (size_t)c * 8, &buf[d + (i * 512 + w * 64) * 8]);
    }
#pragma unroll
    for (int i = 0; i < 4; ++i) {
      int c = i * 512 + tid;
      gload16(sb + (size_t)c * 8, &buf[d + 16384 + (i * 512 + w * 64) * 8]);
    }
  };

  int aidx[8][2], bidx[4][2];
#pragma unroll
  for (int mt = 0; mt < 8; ++mt) {
    int r = wr * 128 + mt * 16 + l15, r7 = r & 7;
#pragma unroll
    for (int ks = 0; ks < 2; ++ks) aidx[mt][ks] = r * 64 + (((ks * 4 + lg) ^ r7) << 3);
  }
#pragma unroll
  for (int nt = 0; nt < 4; ++nt) {
    int r = wc * 64 + nt * 16 + l15, r7 = r & 7;
#pragma unroll
    for (int ks = 0; ks < 2; ++ks) bidx[nt][ks] = r * 64 + (((ks * 4 + lg) ^ r7) << 3);
  }

  f32x4 acc[8][4];
#pragma unroll
  for (int mt = 0; mt < 8; ++mt)
#pragma unroll
    for (int nt = 0; nt < 4; ++nt) acc[mt][nt] = (f32x4){0.f, 0.f, 0.f, 0.f};

  stage(0);
  asm volatile("s_waitcnt vmcnt(0)" ::: "memory");
  __builtin_amdgcn_s_barrier();
  __builtin_amdgcn_sched_barrier(0);

  for (int s = 0; s < 8; ++s) {
    if (s < 7) stage(s + 1);
    int ab = (s & 1) * 32768, bb = ab + 16384;
#pragma unroll
    for (int ks = 0; ks < 2; ++ks) {
      short8 a[8], b[4];
#pragma unroll
      for (int mt = 0; mt < 8; ++mt) a[mt] = *(const short8*)&buf[ab + aidx[mt][ks]];
#pragma unroll
      for (int nt = 0; nt < 4; ++nt) b[nt] = *(const short8*)&buf[bb + bidx[nt][ks]];
#pragma unroll
      for (int mt = 0; mt < 8; ++mt)
#pragma unroll
        for (int nt = 0; nt < 4; ++nt)
          acc[mt][nt] = __builtin_amdgcn_mfma_f32_16x16x32_bf16(a[mt], b[nt], acc[mt][nt], 0, 0, 0);
    }
    asm volatile("s_waitcnt vmcnt(0)" ::: "memory");
    __builtin_amdgcn_s_barrier();
    __builtin_amdgcn_sched_barrier(0);
  }

#pragma unroll
  for (int mt = 0; mt < 8; ++mt) {
    int rbase0 = (wr * 128 + mt * 16) * 256;
#pragma unroll
    for (int nt = 0; nt < 4; ++nt) {
      int col = wc * 64 + nt * 16 + l15;
#pragma unroll
      for (int rr = 0; rr < 4; ++rr) {
        int row = wr * 128 + mt * 16 + lg * 4 + rr;
        float v = s_wt[row] * (acc[mt][nt][rr] + b2v[nt]);
        buf[rbase0 + (lg * 4 + rr) * 256 + col] =
            (unsigned short)(__float_as_uint(v) >> 16);
      }
    }
  }
  __syncthreads();
  unsigned short* ydst = Hp + (size_t)blk * 131072;
#pragma unroll
  for (int i = 0; i < 16; ++i) {
    size_t cidx = (size_t)(i * 512 + tid) * 8;
    *(short8*)&ydst[cidx] = *(const short8*)&buf[cidx];
  }
}

// ---------------- reduce: out[t] = Y[s1] + Y[s2] ----------------
__global__ __launch_bounds__(256) void k_reduce(
    const unsigned short* __restrict__ Y, const float2* __restrict__ inv,
    float* __restrict__ out) {
  int g = blockIdx.x * 256 + threadIdx.x;
#pragma unroll
  for (int it = 0; it < 8; ++it) {
    int t = g >> 5;
    int cw = (g & 31) << 3;
    float2 iv = inv[t];
    int s1 = __float_as_int(iv.x), s2 = __float_as_int(iv.y);
    const unsigned short* y1 = Y + (size_t)(s1 >> 8) * 131072 + (size_t)(s1 & 255) * 256 + cw;
    const unsigned short* y2 = Y + (size_t)(s2 >> 8) * 131072 + (size_t)(s2 & 255) * 256 + cw;
    short8 a = *(const short8*)y1;
    short8 b = *(const short8*)y2;
    float* op = out + (size_t)t * 256 + cw;
    float4 r0, r1;
    r0.x = bf2f((unsigned short)a[0]) + bf2f((unsigned short)b[0]);
    r0.y = bf2f((unsigned short)a[1]) + bf2f((unsigned short)b[1]);
    r0.z = bf2f((unsigned short)a[2]) + bf2f((unsigned short)b[2]);
    r0.w = bf2f((unsigned short)a[3]) + bf2f((unsigned short)b[3]);
    r1.x = bf2f((unsigned short)a[4]) + bf2f((unsigned short)b[4]);
    r1.y = bf2f((unsigned short)a[5]) + bf2f((unsigned short)b[5]);
    r1.z = bf2f((unsigned short)a[6]) + bf2f((unsigned short)b[6]);
    r1.w = bf2f((unsigned short)a[7]) + bf2f((unsigned short)b[7]);
    *(float4*)op = r0;
    *(float4*)(op + 4) = r1;
    g += 2048 * 256;
  }
}

extern "C" void kernel_launch(void* const* d_in, const int* in_sizes, int n_in,
                              void* d_out, int out_size, void* d_ws, size_t ws_size,
                              hipStream_t stream) {
  const float* x    = (const float*)d_in[0];
  const float* gate = (const float*)d_in[1];
  const float* w1   = (const float*)d_in[2];
  const float* b1   = (const float*)d_in[3];
  const float* w2   = (const float*)d_in[4];
  const float* b2   = (const float*)d_in[5];
  float* out = (float*)d_out;
  char* ws = (char*)d_ws;

  unsigned short* xb  = (unsigned short*)(ws);
  unsigned short* P1  = (unsigned short*)(ws + 67108864);
  unsigned short* P2  = (unsigned short*)(ws + 69206016);
  int*    tok_list  = (int*)(ws + 71303168);
  float*  wt_list   = (float*)(ws + 72368128);
  int*    pack      = (int*)(ws + 73433088);
  float2* tkw       = (float2*)(ws + 73957376);
  int*    part_cnt  = (int*)(ws + 75005952);
  float*  part_psum = (float*)(ws + 75071488);
  int*    block_off = (int*)(ws + 75137024);
  int*    cnt_total = (int*)(ws + 75202560);
  double* gate_d    = (double*)(ws + 75235328);
  unsigned short* Hp = (unsigned short*)(ws + 75497472);

  k_wconv<<<512, 256, 0, stream>>>(w1, w2, gate, P1, P2, gate_d);
  k_router<<<512, 256, 0, stream>>>(x, gate_d, xb, pack, tkw, part_cnt, part_psum);
  k_scan<<<1, 512, 0, stream>>>(part_cnt, part_psum, block_off, cnt_total, out);
  k_scatter<<<2048, 64, 0, stream>>>(pack, tkw, block_off, cnt_total, tok_list, wt_list);
  k_gemm1<<<4112, 512, 0, stream>>>(xb, P1, b1, tok_list, cnt_total, Hp);
  k_gemm2c<<<1032, 512, 0, stream>>>(Hp, P2, b2, wt_list, cnt_total);
  k_reduce<<<2048, 256, 0, stream>>>(Hp, tkw, out);
}

// Round 18
// 484.021 us; speedup vs baseline: 1.0507x; 1.0507x over previous
//
#include <hip/hip_runtime.h>

typedef __attribute__((ext_vector_type(8))) short short8;
typedef __attribute__((ext_vector_type(4))) float f32x4;

#define T_TOK  131072
#define DMODEL 256
#define DHID   512
#define NEXP   8

// ---------------- ws layout (bytes) ----------------
// xb        : 0          size 67108864   (T*256 bf16)
// P1        : 67108864   size 2097152    W1 panels [e][kc4][512][64] pre-swizzled
// P2        : 69206016   size 2097152    W2 panels [e][kc8][256][64] pre-swizzled
// tok_list  : 71303168   size 1064960    (padded-base layout)
// wt_list   : 72368128   size 1064960
// pack      : 73433088   size 524288
// tkw/inv   : 73957376   size 1048576
// part_cnt  : 75005952   size 65536
// part_psum : 75071488   size 65536
// block_off : 75137024   size 65536
// cnt_total : 75202560   size 64         int[16]: counts + 256-PADDED bases
// gate_d    : 75235328   size 16384      gate as fp64 [8][256]
// Hp        : 75497472   size 270532608  H panels; gemm2c reuses first half for Y

__device__ __forceinline__ unsigned short f2bf(float f) {
  unsigned int u = __float_as_uint(f);
  u = (u + 0x7FFFu + ((u >> 16) & 1u)) >> 16;
  return (unsigned short)u;
}
__device__ __forceinline__ float bf2f(unsigned short u) {
  return __uint_as_float(((unsigned)u) << 16);
}

__device__ __forceinline__ void gload16(const void* g, void* l) {
  __builtin_amdgcn_global_load_lds(
      (const __attribute__((address_space(1))) void*)g,
      (__attribute__((address_space(3))) void*)l, 16, 0, 0);
}

// ---------------- weight fp32 -> bf16 K-panels (pre-swizzled) + gate fp64 ----------------
__global__ void k_wconv(const float* __restrict__ w1, const float* __restrict__ w2,
                        const float* __restrict__ gate,
                        unsigned short* __restrict__ P1, unsigned short* __restrict__ P2,
                        double* __restrict__ gate_d) {
  int g = blockIdx.x * 256 + threadIdx.x;  // 131072 threads
  if (g < 2048) gate_d[g] = (double)gate[g];
  int e = g >> 14, rem = g & 16383;
  {
    int row = rem >> 5, c = rem & 31;      // 512 rows x 32 chunks (K=256)
    int kc = c >> 3, cs = c & 7;
    const float* s = w1 + ((size_t)e * DHID + row) * DMODEL + c * 8;
    short8 v;
#pragma unroll
    for (int j = 0; j < 8; ++j) v[j] = (short)f2bf(s[j]);
    size_t dc = ((size_t)(e * 4 + kc) * 512 + row) * 8 + (cs ^ (row & 7));
    *(short8*)(P1 + dc * 8) = v;
  }
  {
    int row = rem >> 6, c = rem & 63;      // 256 rows x 64 chunks (K=512)
    int kc = c >> 3, cs = c & 7;
    const float* s = w2 + ((size_t)e * DMODEL + row) * DHID + c * 8;
    short8 v;
#pragma unroll
    for (int j = 0; j < 8; ++j) v[j] = (short)f2bf(s[j]);
    size_t dc = ((size_t)(e * 8 + kc) * 256 + row) * 8 + (cs ^ (row & 7));
    *(short8*)(P2 + dc * 8) = v;
  }
}

// ---------------- router: token-per-lane, fp64 logits via s_load'd gate_d ----------------
__global__ __launch_bounds__(256, 2) void k_router(
    const float* __restrict__ x, const double* __restrict__ gd,
    unsigned short* __restrict__ xb, int* __restrict__ pack, float2* __restrict__ tkw,
    int* __restrict__ part_cnt, float* __restrict__ part_psum) {
  __shared__ float xs[16384];       // 64 rows x 256 (swizzled slots), 64KB
  __shared__ double red[1024];      // 256 thr x 4 experts, 8KB
  __shared__ int s_cnt[NEXP];
  __shared__ float s_ps[NEXP];
  int tid = threadIdx.x;
  int tok = tid & 63, q = tid >> 6;
  int qu = __builtin_amdgcn_readfirstlane(q);

  for (int c = 0; c < 4; ++c) {
    if (tid < NEXP) { s_cnt[tid] = 0; s_ps[tid] = 0.f; }
    int tb = (blockIdx.x << 8) + (c << 6);
    __syncthreads();

#pragma unroll
    for (int i = 0; i < 16; ++i) {
      int idx = i * 256 + tid;
      int row = idx >> 6, c4 = (idx & 63) << 2;
      float4 v = *(const float4*)(x + (size_t)(tb + row) * 256 + c4);
      int sw = row & 31;
      float* xr = xs + row * 256;
      xr[(c4 + 0) ^ sw] = v.x;
      xr[(c4 + 1) ^ sw] = v.y;
      xr[(c4 + 2) ^ sw] = v.z;
      xr[(c4 + 3) ^ sw] = v.w;
      ushort4 u4;
      u4.x = f2bf(v.x); u4.y = f2bf(v.y); u4.z = f2bf(v.z); u4.w = f2bf(v.w);
      *(ushort4*)(xb + (size_t)(tb + row) * 256 + c4) = u4;
    }
    __syncthreads();

    double acc[8] = {0, 0, 0, 0, 0, 0, 0, 0};
    {
      int sw = tok & 31;
      const float* xr = xs + tok * 256;
#pragma unroll 4
      for (int d0 = 0; d0 < 64; ++d0) {
        int d = (qu << 6) + d0;
        double xv = (double)xr[d ^ sw];
#pragma unroll
        for (int e = 0; e < 8; ++e) acc[e] += xv * gd[e * 256 + d];
      }
    }

    double l[8];
#pragma unroll
    for (int j = 0; j < 4; ++j) red[tid * 4 + j] = acc[j];
    __syncthreads();
    if (tid < 64) {
#pragma unroll
      for (int j = 0; j < 4; ++j)
        l[j] = red[tid * 4 + j] + red[(64 + tid) * 4 + j] +
               red[(128 + tid) * 4 + j] + red[(192 + tid) * 4 + j];
    }
    __syncthreads();
#pragma unroll
    for (int j = 0; j < 4; ++j) red[tid * 4 + j] = acc[4 + j];
    __syncthreads();
    if (tid < 64) {
#pragma unroll
      for (int j = 0; j < 4; ++j)
        l[4 + j] = red[tid * 4 + j] + red[(64 + tid) * 4 + j] +
                   red[(128 + tid) * 4 + j] + red[(192 + tid) * 4 + j];
      int t = tb + tid;
      int i1 = 0;
#pragma unroll
      for (int e = 1; e < NEXP; ++e) if (l[e] > l[i1]) i1 = e;
      int i2 = (i1 == 0) ? 1 : 0;
#pragma unroll
      for (int e = 0; e < NEXP; ++e) if (e != i1 && l[e] > l[i2]) i2 = e;
      double m = l[0];
#pragma unroll
      for (int e = 1; e < NEXP; ++e) m = (l[e] > m) ? l[e] : m;
      float pe[NEXP]; float s = 0.f;
#pragma unroll
      for (int e = 0; e < NEXP; ++e) { pe[e] = __expf((float)(l[e] - m)); s += pe[e]; }
      float inv = 1.f / s;
      float p1 = pe[i1] * inv, p2 = pe[i2] * inv;
      float wn = 1.f / (p1 + p2);
      pack[t] = i1 | (i2 << 8);
      tkw[t] = make_float2(p1 * wn, p2 * wn);
      atomicAdd(&s_cnt[i1], 1); atomicAdd(&s_cnt[i2], 1);
#pragma unroll
      for (int e = 0; e < NEXP; ++e) atomicAdd(&s_ps[e], pe[e] * inv);
    }
    __syncthreads();
    if (tid < NEXP) {
      part_cnt[(blockIdx.x * 4 + c) * NEXP + tid] = s_cnt[tid];
      part_psum[(blockIdx.x * 4 + c) * NEXP + tid] = s_ps[tid];
    }
  }
}

// ---------------- scan: offsets, totals, 256-PADDED expert bases, aux loss ----------------
__global__ __launch_bounds__(512) void k_scan(
    const int* __restrict__ part_cnt, const float* __restrict__ part_psum,
    int* __restrict__ block_off, int* __restrict__ cnt_total, float* __restrict__ out) {
  __shared__ float s_ps[NEXP];
  __shared__ int s_ct[NEXP];
  int lane = threadIdx.x & 63, wv = threadIdx.x >> 6;
  int base = lane * 32;
  int lsum = 0; float ps = 0.f;
#pragma unroll 8
  for (int j = 0; j < 32; ++j) {
    lsum += part_cnt[(base + j) * NEXP + wv];
    ps += part_psum[(base + j) * NEXP + wv];
  }
  int incl = lsum;
#pragma unroll
  for (int d = 1; d < 64; d <<= 1) { int t = __shfl_up(incl, d); if (lane >= d) incl += t; }
  int run = incl - lsum;
#pragma unroll 8
  for (int j = 0; j < 32; ++j) {
    int v = part_cnt[(base + j) * NEXP + wv];
    block_off[(base + j) * NEXP + wv] = run;
    run += v;
  }
#pragma unroll
  for (int d = 32; d; d >>= 1) ps += __shfl_xor(ps, d);
  int total = __shfl(incl, 63);
  if (lane == 0) { cnt_total[wv] = total; s_ct[wv] = total; s_ps[wv] = ps; }
  __syncthreads();
  if (threadIdx.x == 0) {
    double aux = 0.0; int rb = 0;
    for (int e = 0; e < NEXP; ++e) {
      aux += ((double)s_ct[e] / 131072.0) * ((double)s_ps[e] / 131072.0);
      cnt_total[8 + e] = rb;
      rb += (s_ct[e] + 255) & ~255;   // 256-aligned padded base
    }
    out[33554432] = (float)(8.0 * aux);
  }
}

// ---------------- scatter: per-expert lists + inverse map (over tkw) ----------------
__global__ void k_scatter(const int* __restrict__ pack, float2* tkw,
                          const int* __restrict__ block_off, const int* __restrict__ cnt_total,
                          int* __restrict__ tok_list, float* __restrict__ wt_list) {
  __shared__ int s_loc[NEXP];
  int tid = threadIdx.x;
  if (tid < NEXP) s_loc[tid] = 0;
  __syncthreads();
  int t = (blockIdx.x << 6) + tid;
  int p = pack[t];
  float2 wv = tkw[t];
  int e1 = p & 255, e2 = (p >> 8) & 255;
  int o1 = block_off[blockIdx.x * NEXP + e1];
  int p1 = atomicAdd(&s_loc[e1], 1);
  int i1 = cnt_total[8 + e1] + o1 + p1;
  tok_list[i1] = t; wt_list[i1] = wv.x;
  int o2 = block_off[blockIdx.x * NEXP + e2];
  int p2 = atomicAdd(&s_loc[e2], 1);
  int i2 = cnt_total[8 + e2] + o2 + p2;
  tok_list[i2] = t; wt_list[i2] = wv.y;
  tkw[t] = make_float2(__int_as_float(i1), __int_as_float(i2));
}

// ---------------- grouped GEMM1 + silu -> Hp panels ----------------
// R18: M=128 x N=128 (ni in 0..3), BK=64 dbuf A+B, LDS 64KB -> 2 blocks/CU
// (4 waves/SIMD: cross-block overlap fills the drain stalls). Epilogue = R16
// form (bounce + panel-slot-identity store). acc[4][2] per wave (64x32).
__global__ __launch_bounds__(512, 2) void k_gemm1(
    const unsigned short* __restrict__ xb, const unsigned short* __restrict__ P1,
    const float* __restrict__ b1, const int* __restrict__ tok_list,
    const int* __restrict__ cnt_total, unsigned short* __restrict__ Hp) {
  __shared__ __align__(16) unsigned short buf[32768];  // A0 A1 B0 B1: 8192 u16 each
  __shared__ int s_tok[128];

  int bid = (blockIdx.x & 7) * 1029 + (blockIdx.x >> 3);  // grid 8232 = 8*1029
  int e = -1, loc = 0, cum = 0, cnte = 0;
#pragma unroll
  for (int ee = 0; ee < NEXP; ++ee) {
    int ct = cnt_total[ee];
    int nb = ((ct + 127) >> 7) * 4;
    if (e < 0 && bid < cum + nb) { e = ee; loc = bid - cum; cnte = ct; }
    cum += nb;
  }
  if (e < 0) return;
  int mi = loc >> 2, ni = loc & 3;
  int nv = cnte - (mi << 7); if (nv > 128) nv = 128;
  int hbp = cnt_total[8 + e];

  int tid = threadIdx.x;
  int lane = tid & 63, w = tid >> 6, l15 = lane & 15, lg = lane >> 4;
  int wr = w >> 2, wc = w & 3;   // 2M x 4N waves; per-wave 64 rows x 32 cols

  float b1v[2];
#pragma unroll
  for (int nt = 0; nt < 2; ++nt)
    b1v[nt] = b1[e * DHID + ni * 128 + wc * 32 + nt * 16 + l15];

  if (tid < 128) s_tok[tid] = tok_list[hbp + (mi << 7) + (tid < nv ? tid : nv - 1)];
  __syncthreads();

  // per-thread staging bases. A: slot t=i*512+tid -> row=i*64+(tid>>3), c=tid&7.
  int arow0 = tid >> 3, acs = tid & 7;
  const unsigned short* pa[2];
#pragma unroll
  for (int i = 0; i < 2; ++i) {
    int row = i * 64 + arow0;
    pa[i] = xb + (size_t)s_tok[row] * DMODEL + ((acs ^ (row & 7)) << 3);
  }
  // B: contiguous 16KB quarter-panel slice per kc (pre-swizzled in P1)
  const unsigned short* pb = P1 + ((size_t)(e * 4) * 512 + ni * 128) * 64;

  auto stage = [&](int kc) {
    int ab = (kc & 1) * 8192, bb = 16384 + (kc & 1) * 8192;
#pragma unroll
    for (int i = 0; i < 2; ++i)
      gload16(pa[i] + kc * 64, &buf[(size_t)(ab + (i * 512 + w * 64) * 8)]);
    const unsigned short* src = pb + (size_t)kc * 32768;
#pragma unroll
    for (int i = 0; i < 2; ++i) {
      int c = i * 512 + tid;
      gload16(src + (size_t)c * 8, &buf[(size_t)(bb + (i * 512 + w * 64) * 8)]);
    }
  };

  // precomputed per-thread u16 LDS indices
  int aidx[4][2], bidx[2][2];
#pragma unroll
  for (int mt = 0; mt < 4; ++mt) {
    int r = wr * 64 + mt * 16 + l15, r7 = r & 7;
#pragma unroll
    for (int ks = 0; ks < 2; ++ks) aidx[mt][ks] = r * 64 + (((ks * 4 + lg) ^ r7) << 3);
  }
#pragma unroll
  for (int nt = 0; nt < 2; ++nt) {
    int r = wc * 32 + nt * 16 + l15, r7 = r & 7;
#pragma unroll
    for (int ks = 0; ks < 2; ++ks) bidx[nt][ks] = r * 64 + (((ks * 4 + lg) ^ r7) << 3);
  }

  f32x4 acc[4][2];
#pragma unroll
  for (int mt = 0; mt < 4; ++mt)
#pragma unroll
    for (int nt = 0; nt < 2; ++nt) acc[mt][nt] = (f32x4){0.f, 0.f, 0.f, 0.f};

  stage(0);
  asm volatile("s_waitcnt vmcnt(0)" ::: "memory");
  __builtin_amdgcn_s_barrier();
  __builtin_amdgcn_sched_barrier(0);

  for (int s = 0; s < 4; ++s) {
    if (s < 3) stage(s + 1);
    int ab = (s & 1) * 8192, bb = 16384 + (s & 1) * 8192;
#pragma unroll
    for (int ks = 0; ks < 2; ++ks) {
      short8 a[4], b[2];
#pragma unroll
      for (int mt = 0; mt < 4; ++mt) a[mt] = *(const short8*)&buf[ab + aidx[mt][ks]];
#pragma unroll
      for (int nt = 0; nt < 2; ++nt) b[nt] = *(const short8*)&buf[bb + bidx[nt][ks]];
#pragma unroll
      for (int mt = 0; mt < 4; ++mt)
#pragma unroll
        for (int nt = 0; nt < 2; ++nt)
          acc[mt][nt] = __builtin_amdgcn_mfma_f32_16x16x32_bf16(a[mt], b[nt], acc[mt][nt], 0, 0, 0);
    }
    asm volatile("s_waitcnt vmcnt(0)" ::: "memory");
    __builtin_amdgcn_s_barrier();
    __builtin_amdgcn_sched_barrier(0);
  }

  // epilogue pass 1: silu -> bounce [128 rows][128 cols], slot perm
  // p = (c3&8) | ((c3&7)^(row&7)); content chunk c3 lands at slot p.
#pragma unroll
  for (int mt = 0; mt < 4; ++mt) {
    int rbase0 = (wr * 64 + mt * 16) * 128;
#pragma unroll
    for (int nt = 0; nt < 2; ++nt) {
      int col = wc * 32 + nt * 16 + l15;
      int c3 = col >> 3, c7 = col & 7;
#pragma unroll
      for (int rr = 0; rr < 4; ++rr) {
        int lr = lg * 4 + rr;                // local row-in-16
        int r7 = lr & 7;                     // row&7 (16-row blocks are 0 mod 8)
        int p = (c3 & 8) | ((c3 & 7) ^ r7);
        float z = acc[mt][nt][rr] + b1v[nt];
        float sv = z * __builtin_amdgcn_rcpf(1.f + __expf(-z));
        buf[rbase0 + lr * 128 + (p << 3) + c7] =
            (unsigned short)(__float_as_uint(sv) >> 16);
      }
    }
  }
  __syncthreads();
  // epilogue pass 2: bounce raw slot s holds content (s&7)^(row&7) within its
  // kc group -> panel slot = raw slot (identity). 4 instrs/thread.
  {
    int blk = (hbp >> 8) + (mi >> 1);
    int rbase = (mi & 1) * 128;
    short8 z8 = {0, 0, 0, 0, 0, 0, 0, 0};
#pragma unroll
    for (int i = 0; i < 4; ++i) {
      int t = i * 512 + tid;
      int row = t >> 4, s = t & 15;
      short8 v = (row < nv) ? *(const short8*)&buf[row * 128 + s * 8] : z8;
      size_t dc = ((size_t)(blk * 8 + ni * 2 + (s >> 3)) * 256 + rbase + row) * 8 + (s & 7);
      *(short8*)&Hp[dc * 8] = v;
    }
  }
}

// ---------------- GEMM2 compute: K-loop w/ precomputed indices, trunc epilogue ----------
__global__ __launch_bounds__(512, 2) void k_gemm2c(
    unsigned short* Hp, const unsigned short* __restrict__ P2,
    const float* __restrict__ b2, const float* __restrict__ wt_list,
    const int* __restrict__ cnt_total) {
  __shared__ __align__(16) unsigned short buf[65536];
  __shared__ float s_wt[256];

  int bid = (blockIdx.x & 7) * 129 + (blockIdx.x >> 3);  // grid 1032 = 8*129
  int e = -1, mi = 0, cum = 0, cnte = 0;
#pragma unroll
  for (int ee = 0; ee < NEXP; ++ee) {
    int ct = cnt_total[ee];
    int nb = (ct + 255) >> 8;
    if (e < 0 && bid < cum + nb) { e = ee; mi = bid - cum; cnte = ct; }
    cum += nb;
  }
  if (e < 0) return;
  int nv = cnte - (mi << 8); if (nv > 256) nv = 256;
  int hbp = cnt_total[8 + e];
  int blk = (hbp >> 8) + mi;

  int tid = threadIdx.x;
  int lane = tid & 63, w = tid >> 6, l15 = lane & 15, lg = lane >> 4;
  int wr = w >> 2, wc = w & 3;

  float b2v[4];
#pragma unroll
  for (int nt = 0; nt < 4; ++nt)
    b2v[nt] = b2[e * DMODEL + wc * 64 + nt * 16 + l15];

  if (tid < 256) s_wt[tid] = (tid < nv) ? wt_list[hbp + (mi << 8) + tid] : 0.f;
  __syncthreads();

  auto stage = [&](int s) {
    int d = (s & 1) * 32768;
    const unsigned short* sa = Hp + (size_t)(blk * 8 + s) * 16384;
    const unsigned short* sb = P2 + (size_t)(e * 8 + s) * 16384;
#pragma unroll
    for (int i = 0; i < 4; ++i) {
      int c = i * 512 + tid;
      gload16(sa + (size_t)c * 8, &buf[d + (i * 512 + w * 64) * 8]);
    }
#pragma unroll
    for (int i = 0; i < 4; ++i) {
      int c = i * 512 + tid;
      gload16(sb + (size_t)c * 8, &buf[d + 16384 + (i * 512 + w * 64) * 8]);
    }
  };

  int aidx[8][2], bidx[4][2];
#pragma unroll
  for (int mt = 0; mt < 8; ++mt) {
    int r = wr * 128 + mt * 16 + l15, r7 = r & 7;
#pragma unroll
    for (int ks = 0; ks < 2; ++ks) aidx[mt][ks] = r * 64 + (((ks * 4 + lg) ^ r7) << 3);
  }
#pragma unroll
  for (int nt = 0; nt < 4; ++nt) {
    int r = wc * 64 + nt * 16 + l15, r7 = r & 7;
#pragma unroll
    for (int ks = 0; ks < 2; ++ks) bidx[nt][ks] = r * 64 + (((ks * 4 + lg) ^ r7) << 3);
  }

  f32x4 acc[8][4];
#pragma unroll
  for (int mt = 0; mt < 8; ++mt)
#pragma unroll
    for (int nt = 0; nt < 4; ++nt) acc[mt][nt] = (f32x4){0.f, 0.f, 0.f, 0.f};

  stage(0);
  asm volatile("s_waitcnt vmcnt(0)" ::: "memory");
  __builtin_amdgcn_s_barrier();
  __builtin_amdgcn_sched_barrier(0);

  for (int s = 0; s < 8; ++s) {
    if (s < 7) stage(s + 1);
    int ab = (s & 1) * 32768, bb = ab + 16384;
#pragma unroll
    for (int ks = 0; ks < 2; ++ks) {
      short8 a[8], b[4];
#pragma unroll
      for (int mt = 0; mt < 8; ++mt) a[mt] = *(const short8*)&buf[ab + aidx[mt][ks]];
#pragma unroll
      for (int nt = 0; nt < 4; ++nt) b[nt] = *(const short8*)&buf[bb + bidx[nt][ks]];
#pragma unroll
      for (int mt = 0; mt < 8; ++mt)
#pragma unroll
        for (int nt = 0; nt < 4; ++nt)
          acc[mt][nt] = __builtin_amdgcn_mfma_f32_16x16x32_bf16(a[mt], b[nt], acc[mt][nt], 0, 0, 0);
    }
    asm volatile("s_waitcnt vmcnt(0)" ::: "memory");
    __builtin_amdgcn_s_barrier();
    __builtin_amdgcn_sched_barrier(0);
  }

#pragma unroll
  for (int mt = 0; mt < 8; ++mt) {
    int rbase0 = (wr * 128 + mt * 16) * 256;
#pragma unroll
    for (int nt = 0; nt < 4; ++nt) {
      int col = wc * 64 + nt * 16 + l15;
#pragma unroll
      for (int rr = 0; rr < 4; ++rr) {
        int row = wr * 128 + mt * 16 + lg * 4 + rr;
        float v = s_wt[row] * (acc[mt][nt][rr] + b2v[nt]);
        buf[rbase0 + (lg * 4 + rr) * 256 + col] =
            (unsigned short)(__float_as_uint(v) >> 16);
      }
    }
  }
  __syncthreads();
  unsigned short* ydst = Hp + (size_t)blk * 131072;
#pragma unroll
  for (int i = 0; i < 16; ++i) {
    size_t cidx = (size_t)(i * 512 + tid) * 8;
    *(short8*)&ydst[cidx] = *(const short8*)&buf[cidx];
  }
}

// ---------------- reduce: out[t] = Y[s1] + Y[s2] ----------------
__global__ __launch_bounds__(256) void k_reduce(
    const unsigned short* __restrict__ Y, const float2* __restrict__ inv,
    float* __restrict__ out) {
  int g = blockIdx.x * 256 + threadIdx.x;
#pragma unroll
  for (int it = 0; it < 8; ++it) {
    int t = g >> 5;
    int cw = (g & 31) << 3;
    float2 iv = inv[t];
    int s1 = __float_as_int(iv.x), s2 = __float_as_int(iv.y);
    const unsigned short* y1 = Y + (size_t)(s1 >> 8) * 131072 + (size_t)(s1 & 255) * 256 + cw;
    const unsigned short* y2 = Y + (size_t)(s2 >> 8) * 131072 + (size_t)(s2 & 255) * 256 + cw;
    short8 a = *(const short8*)y1;
    short8 b = *(const short8*)y2;
    float* op = out + (size_t)t * 256 + cw;
    float4 r0, r1;
    r0.x = bf2f((unsigned short)a[0]) + bf2f((unsigned short)b[0]);
    r0.y = bf2f((unsigned short)a[1]) + bf2f((unsigned short)b[1]);
    r0.z = bf2f((unsigned short)a[2]) + bf2f((unsigned short)b[2]);
    r0.w = bf2f((unsigned short)a[3]) + bf2f((unsigned short)b[3]);
    r1.x = bf2f((unsigned short)a[4]) + bf2f((unsigned short)b[4]);
    r1.y = bf2f((unsigned short)a[5]) + bf2f((unsigned short)b[5]);
    r1.z = bf2f((unsigned short)a[6]) + bf2f((unsigned short)b[6]);
    r1.w = bf2f((unsigned short)a[7]) + bf2f((unsigned short)b[7]);
    *(float4*)op = r0;
    *(float4*)(op + 4) = r1;
    g += 2048 * 256;
  }
}

extern "C" void kernel_launch(void* const* d_in, const int* in_sizes, int n_in,
                              void* d_out, int out_size, void* d_ws, size_t ws_size,
                              hipStream_t stream) {
  const float* x    = (const float*)d_in[0];
  const float* gate = (const float*)d_in[1];
  const float* w1   = (const float*)d_in[2];
  const float* b1   = (const float*)d_in[3];
  const float* w2   = (const float*)d_in[4];
  const float* b2   = (const float*)d_in[5];
  float* out = (float*)d_out;
  char* ws = (char*)d_ws;

  unsigned short* xb  = (unsigned short*)(ws);
  unsigned short* P1  = (unsigned short*)(ws + 67108864);
  unsigned short* P2  = (unsigned short*)(ws + 69206016);
  int*    tok_list  = (int*)(ws + 71303168);
  float*  wt_list   = (float*)(ws + 72368128);
  int*    pack      = (int*)(ws + 73433088);
  float2* tkw       = (float2*)(ws + 73957376);
  int*    part_cnt  = (int*)(ws + 75005952);
  float*  part_psum = (float*)(ws + 75071488);
  int*    block_off = (int*)(ws + 75137024);
  int*    cnt_total = (int*)(ws + 75202560);
  double* gate_d    = (double*)(ws + 75235328);
  unsigned short* Hp = (unsigned short*)(ws + 75497472);

  k_wconv<<<512, 256, 0, stream>>>(w1, w2, gate, P1, P2, gate_d);
  k_router<<<512, 256, 0, stream>>>(x, gate_d, xb, pack, tkw, part_cnt, part_psum);
  k_scan<<<1, 512, 0, stream>>>(part_cnt, part_psum, block_off, cnt_total, out);
  k_scatter<<<2048, 64, 0, stream>>>(pack, tkw, block_off, cnt_total, tok_list, wt_list);
  k_gemm1<<<8232, 512, 0, stream>>>(xb, P1, b1, tok_list, cnt_total, Hp);
  k_gemm2c<<<1032, 512, 0, stream>>>(Hp, P2, b2, wt_list, cnt_total);
  k_reduce<<<2048, 256, 0, stream>>>(Hp, tkw, out);
}